// Round 1
// baseline (68.498 us; speedup 1.0000x reference)
//
#include <hip/hip_runtime.h>
#include <math.h>

constexpr int M_TOK = 8;
constexpr int N_OUT = 8192;
constexpr int K_IN  = 8192;
constexpr int KG    = 64;   // K / G, G = 128
constexpr int R_N   = 4;    // output rows per wave

// ---------------- Kernel 1: per-token symmetric int8 fake-quant ----------------
// 8 blocks (one per token row) x 1024 threads; each thread handles 8 floats.
__global__ __launch_bounds__(1024) void act_quant_kernel(const float* __restrict__ x,
                                                         float* __restrict__ xq) {
    const int row = blockIdx.x;
    const float4* xr = reinterpret_cast<const float4*>(x + (size_t)row * K_IN);
    float4* oq = reinterpret_cast<float4*>(xq + (size_t)row * K_IN);
    const int tid = threadIdx.x;

    float4 v0 = xr[tid * 2];
    float4 v1 = xr[tid * 2 + 1];

    float m = fmaxf(
        fmaxf(fmaxf(fabsf(v0.x), fabsf(v0.y)), fmaxf(fabsf(v0.z), fabsf(v0.w))),
        fmaxf(fmaxf(fabsf(v1.x), fabsf(v1.y)), fmaxf(fabsf(v1.z), fabsf(v1.w))));

    // wave (64-lane) butterfly max
    #pragma unroll
    for (int off = 32; off; off >>= 1) m = fmaxf(m, __shfl_xor(m, off));

    __shared__ float smax[16];
    if ((tid & 63) == 0) smax[tid >> 6] = m;
    __syncthreads();
    float mm = smax[0];
    #pragma unroll
    for (int i = 1; i < 16; ++i) mm = fmaxf(mm, smax[i]);

    // match numpy exactly: s = max/127.0 (true division), clamp to 1e-8
    const float s = fmaxf(mm / 127.0f, 1e-8f);

    auto quant = [&](float v) -> float {
        float q = rintf(v / s);              // numpy round = half-to-even = rintf
        q = fminf(fmaxf(q, -127.0f), 127.0f);
        return q * s;
    };

    float4 o0, o1;
    o0.x = quant(v0.x); o0.y = quant(v0.y); o0.z = quant(v0.z); o0.w = quant(v0.w);
    o1.x = quant(v1.x); o1.y = quant(v1.y); o1.z = quant(v1.z); o1.w = quant(v1.w);
    oq[tid * 2]     = o0;
    oq[tid * 2 + 1] = o1;
}

// ---------------- Kernel 2: dequant + skinny GEMM ----------------
// One wave handles R_N=4 output rows (n) across full K; 4 waves per block.
// Per k-iteration (256 k per wave): lane loads 4 int4 weight chunks + 8 float4
// xq chunks; acc[4][8] in registers; butterfly-reduce at the end.
__global__ __launch_bounds__(256) void qlin_kernel(const float* __restrict__ xq,
                                                   const int* __restrict__ qw,
                                                   const float* __restrict__ scales,
                                                   const float* __restrict__ bias,
                                                   float* __restrict__ out) {
    const int wave = blockIdx.x * 4 + (threadIdx.x >> 6);
    const int lane = threadIdx.x & 63;
    const int n0 = wave * R_N;

    float acc[R_N][M_TOK];
    #pragma unroll
    for (int r = 0; r < R_N; ++r)
        #pragma unroll
        for (int m = 0; m < M_TOK; ++m) acc[r][m] = 0.0f;

    const int lk = lane * 4;

    for (int kb = 0; kb < K_IN; kb += 256) {
        const int k = kb + lk;
        const int g = k >> 7;  // group index; 4 consecutive k share one group

        float4 xv[M_TOK];
        #pragma unroll
        for (int m = 0; m < M_TOK; ++m)
            xv[m] = *reinterpret_cast<const float4*>(xq + (size_t)m * K_IN + k);

        #pragma unroll
        for (int r = 0; r < R_N; ++r) {
            const int4 c =
                *reinterpret_cast<const int4*>(qw + (size_t)(n0 + r) * K_IN + k);
            const float sc = scales[(size_t)(n0 + r) * KG + g];
            const float w0 = (float)c.x * sc;
            const float w1 = (float)c.y * sc;
            const float w2 = (float)c.z * sc;
            const float w3 = (float)c.w * sc;
            #pragma unroll
            for (int m = 0; m < M_TOK; ++m) {
                float a = acc[r][m];
                a = fmaf(w0, xv[m].x, a);
                a = fmaf(w1, xv[m].y, a);
                a = fmaf(w2, xv[m].z, a);
                a = fmaf(w3, xv[m].w, a);
                acc[r][m] = a;
            }
        }
    }

    // full butterfly reduce -> every lane holds each (r,m) total
    #pragma unroll
    for (int r = 0; r < R_N; ++r)
        #pragma unroll
        for (int m = 0; m < M_TOK; ++m) {
            float v = acc[r][m];
            #pragma unroll
            for (int off = 32; off; off >>= 1) v += __shfl_xor(v, off);
            acc[r][m] = v;
        }

    // lane (r*8 + m) writes out[m][n0+r]; static-index select (no scratch spill)
    if (lane < R_N * M_TOK) {
        const int rsel = lane >> 3;
        const int msel = lane & 7;
        float myv = 0.0f;
        #pragma unroll
        for (int r = 0; r < R_N; ++r)
            #pragma unroll
            for (int m = 0; m < M_TOK; ++m)
                if (r == rsel && m == msel) myv = acc[r][m];
        out[(size_t)msel * N_OUT + n0 + rsel] = myv + bias[n0 + rsel];
    }
}

extern "C" void kernel_launch(void* const* d_in, const int* in_sizes, int n_in,
                              void* d_out, int out_size, void* d_ws, size_t ws_size,
                              hipStream_t stream) {
    const float* x      = (const float*)d_in[0];
    const int*   qw     = (const int*)d_in[1];
    const float* scales = (const float*)d_in[2];
    const float* bias   = (const float*)d_in[3];
    float* out = (float*)d_out;
    float* xq  = (float*)d_ws;  // M*K floats = 256 KiB scratch

    act_quant_kernel<<<M_TOK, 1024, 0, stream>>>(x, xq);

    const int waves  = N_OUT / R_N;        // 2048
    const int blocks = waves / 4;          // 512 blocks x 256 threads
    qlin_kernel<<<blocks, 256, 0, stream>>>(xq, qw, scales, bias, out);
}